// Round 2
// baseline (408.947 us; speedup 1.0000x reference)
//
#include <hip/hip_runtime.h>
#include <hip/hip_bf16.h>
#include <cstdint>
#include <cstddef>

typedef __bf16 bf16_t;
typedef __attribute__((ext_vector_type(8))) __bf16 bf16x8;
typedef __attribute__((ext_vector_type(4))) float f32x4;

#define KK 8
#define BENT 4096
#define MDIM 4096
#define HIN 512
#define HENC 256
#define HCORE 512
#define HCTX 256
#define HSTATE 512
#define NPAIR (BENT*(KK-1))   // 28672

// ---------------- activation ----------------
template<int ACT>
__device__ __forceinline__ float act_f(float v) {
  if constexpr (ACT == 1) return v > 0.f ? v : expm1f(v);        // ELU
  else if constexpr (ACT == 2) return v > 0.f ? v : 0.f;         // ReLU
  else if constexpr (ACT == 3) return 1.f / (1.f + __expf(-v));  // sigmoid
  else return v;
}

// ---------------- 8-element bf16 fragment load (with fp32->bf16 cvt) ----------------
__device__ __forceinline__ bf16x8 load8(const bf16_t* p) {
  return *(const bf16x8*)p;
}
__device__ __forceinline__ bf16x8 load8(const float* p) {
  const float4 f0 = ((const float4*)p)[0];
  const float4 f1 = ((const float4*)p)[1];
  bf16x8 r;
  r[0] = (bf16_t)f0.x; r[1] = (bf16_t)f0.y; r[2] = (bf16_t)f0.z; r[3] = (bf16_t)f0.w;
  r[4] = (bf16_t)f1.x; r[5] = (bf16_t)f1.y; r[6] = (bf16_t)f1.z; r[7] = (bf16_t)f1.w;
  return r;
}

// ---------------- transpose+convert: fp32 [R,C] -> bf16 [C,R] ----------------
__global__ __launch_bounds__(256)
void transpose_k(const float* __restrict__ src, bf16_t* __restrict__ dst, int R, int C) {
  __shared__ float tile[32][33];
  int tx = threadIdx.x, ty = threadIdx.y;
  int c0 = blockIdx.x * 32, r0 = blockIdx.y * 32;
  #pragma unroll
  for (int i = 0; i < 4; ++i)
    tile[ty + 8*i][tx] = src[(size_t)(r0 + ty + 8*i) * C + c0 + tx];
  __syncthreads();
  #pragma unroll
  for (int i = 0; i < 4; ++i)
    dst[(size_t)(c0 + ty + 8*i) * R + r0 + tx] = (bf16_t)tile[tx][ty + 8*i];
}

// ---------------- GEMM: C = act(A @ Bt^T + bias) ----------------
// A: [M,K] row-major, fp32 or bf16 (converted to bf16 during staging).
// Bt: [N,K] bf16 (pre-transposed weight). bias: fp32.
// OUTF bit0: write bf16 to Cb (stride ldc); bit1: write fp32 to Cf (stride ldcf).
// Block tile 64x64, BK=64, 256 threads (4 waves), wave = 32x32 via 2x2 MFMA 16x16x32.
template<int ACT, int OUTF, typename AT>
__global__ __launch_bounds__(256)
void gemm_bt(const AT* __restrict__ A, const bf16_t* __restrict__ Bt,
             const float* __restrict__ bias, bf16_t* __restrict__ Cb,
             float* __restrict__ Cf, int M, int N, int Kd, int ldc, int ldcf) {
  const int tid  = threadIdx.x;
  const int lane = tid & 63;
  const int wave = tid >> 6;
  const int wm = wave >> 1, wn = wave & 1;
  const int quad = lane >> 4;
  const int l16  = lane & 15;
  const int bm0 = blockIdx.y * 64;
  const int bn0 = blockIdx.x * 64;

  __shared__ __align__(16) bf16_t Alds[64 * 72];
  __shared__ __align__(16) bf16_t Blds[64 * 72];

  f32x4 acc[2][2];
  #pragma unroll
  for (int i = 0; i < 2; ++i)
    #pragma unroll
    for (int j = 0; j < 2; ++j)
      acc[i][j] = f32x4{0.f, 0.f, 0.f, 0.f};

  const int srow = tid >> 3;   // 0..31
  const int sgrp = tid & 7;    // 0..7

  for (int k0 = 0; k0 < Kd; k0 += 64) {
    const bf16x8 va0 = load8(A  + (size_t)(bm0 + srow)      * Kd + k0 + sgrp * 8);
    const bf16x8 va1 = load8(A  + (size_t)(bm0 + srow + 32) * Kd + k0 + sgrp * 8);
    const bf16x8 vb0 = load8(Bt + (size_t)(bn0 + srow)      * Kd + k0 + sgrp * 8);
    const bf16x8 vb1 = load8(Bt + (size_t)(bn0 + srow + 32) * Kd + k0 + sgrp * 8);
    *(bf16x8*)&Alds[(srow)      * 72 + sgrp * 8] = va0;
    *(bf16x8*)&Alds[(srow + 32) * 72 + sgrp * 8] = va1;
    *(bf16x8*)&Blds[(srow)      * 72 + sgrp * 8] = vb0;
    *(bf16x8*)&Blds[(srow + 32) * 72 + sgrp * 8] = vb1;
    __syncthreads();
    #pragma unroll
    for (int ks = 0; ks < 2; ++ks) {
      bf16x8 a0 = *(const bf16x8*)&Alds[(32*wm +      l16) * 72 + ks*32 + quad*8];
      bf16x8 a1 = *(const bf16x8*)&Alds[(32*wm + 16 + l16) * 72 + ks*32 + quad*8];
      bf16x8 b0 = *(const bf16x8*)&Blds[(32*wn +      l16) * 72 + ks*32 + quad*8];
      bf16x8 b1 = *(const bf16x8*)&Blds[(32*wn + 16 + l16) * 72 + ks*32 + quad*8];
      acc[0][0] = __builtin_amdgcn_mfma_f32_16x16x32_bf16(a0, b0, acc[0][0], 0, 0, 0);
      acc[0][1] = __builtin_amdgcn_mfma_f32_16x16x32_bf16(a0, b1, acc[0][1], 0, 0, 0);
      acc[1][0] = __builtin_amdgcn_mfma_f32_16x16x32_bf16(a1, b0, acc[1][0], 0, 0, 0);
      acc[1][1] = __builtin_amdgcn_mfma_f32_16x16x32_bf16(a1, b1, acc[1][1], 0, 0, 0);
    }
    __syncthreads();
  }

  // epilogue: C/D layout col = lane&15, row = quad*4 + reg  [verified m89/m91]
  #pragma unroll
  for (int mt = 0; mt < 2; ++mt)
    #pragma unroll
    for (int nt = 0; nt < 2; ++nt) {
      const int gcol = bn0 + 32*wn + 16*nt + l16;
      const float bv = bias[gcol];
      #pragma unroll
      for (int r = 0; r < 4; ++r) {
        const int grow = bm0 + 32*wm + 16*mt + quad*4 + r;
        float v = acc[mt][nt][r] + bv;
        v = act_f<ACT>(v);
        if constexpr (OUTF & 1) Cb[(size_t)grow * ldc  + gcol] = (bf16_t)v;
        if constexpr (OUTF & 2) Cf[(size_t)grow * ldcf + gcol] = v;
      }
    }
}

// ---------------- pair gather: core_in[r] = [state1[partner], state1[self]] ----------------
__global__ __launch_bounds__(64)
void gather_k(const bf16_t* __restrict__ state1, bf16_t* __restrict__ core_in) {
  const int r = blockIdx.x;          // 0..28671
  const int t = threadIdx.x;         // 0..63
  const int e = r / 7;               // entity
  const int j = r - e * 7;
  const int i = e & 7;
  const int p = (j < i) ? j : j + 1;
  const int pent = (e & ~7) + p;
  const uint4* src = (t < 32)
      ? ((const uint4*)(state1 + (size_t)pent * HENC) + t)
      : ((const uint4*)(state1 + (size_t)e    * HENC) + (t - 32));
  ((uint4*)(core_in + (size_t)r * (2 * HENC)))[t] = *src;
}

// ---------------- attention: att[r] = sigmoid(dot(core_out[r], W_att) + b) ----------------
__global__ __launch_bounds__(256)
void att_k(const bf16_t* __restrict__ co, const float* __restrict__ Watt,
           const float* __restrict__ batt, float* __restrict__ att) {
  const int row  = blockIdx.x * 4 + (threadIdx.x >> 6);
  const int lane = threadIdx.x & 63;
  bf16x8 v = *(const bf16x8*)(co + (size_t)row * HCORE + lane * 8);
  const float4 w0 = ((const float4*)(Watt + lane * 8))[0];
  const float4 w1 = ((const float4*)(Watt + lane * 8))[1];
  float s = (float)v[0]*w0.x + (float)v[1]*w0.y + (float)v[2]*w0.z + (float)v[3]*w0.w
          + (float)v[4]*w1.x + (float)v[5]*w1.y + (float)v[6]*w1.z + (float)v[7]*w1.w;
  #pragma unroll
  for (int o = 32; o > 0; o >>= 1) s += __shfl_down(s, o, 64);
  if (lane == 0) att[row] = 1.f / (1.f + __expf(-(s + batt[0])));
}

// ---------------- effect sum + total concat ----------------
// total[e] = [state1[e] (256) | sum_j att*ctx (256) | x (512, written by gemm1)]
__global__ __launch_bounds__(256)
void effect_k(const float* __restrict__ att, const bf16_t* __restrict__ ctx,
              const bf16_t* __restrict__ state1, bf16_t* __restrict__ total) {
  const int e = blockIdx.x;     // 0..4095
  const int c = threadIdx.x;    // 0..255
  float s = 0.f;
  #pragma unroll
  for (int j = 0; j < 7; ++j)
    s += att[e * 7 + j] * (float)ctx[(size_t)(e * 7 + j) * HCTX + c];
  total[(size_t)e * 1024 + 256 + c] = (bf16_t)s;
  total[(size_t)e * 1024 + c]       = state1[(size_t)e * HENC + c];
}

extern "C" void kernel_launch(void* const* d_in, const int* in_sizes, int n_in,
                              void* d_out, int out_size, void* d_ws, size_t ws_size,
                              hipStream_t stream) {
  const float* inputs = (const float*)d_in[0];
  const float* state  = (const float*)d_in[1];
  const float* W_in   = (const float*)d_in[2];
  const float* b_in   = (const float*)d_in[3];
  const float* W_enc  = (const float*)d_in[4];
  const float* b_enc  = (const float*)d_in[5];
  const float* W_core = (const float*)d_in[6];
  const float* b_core = (const float*)d_in[7];
  const float* W_ctx  = (const float*)d_in[8];
  const float* b_ctx  = (const float*)d_in[9];
  const float* W_att  = (const float*)d_in[10];
  const float* b_att  = (const float*)d_in[11];
  const float* W_rec  = (const float*)d_in[12];
  const float* b_rec  = (const float*)d_in[13];
  const float* W_out  = (const float*)d_in[14];
  const float* b_out  = (const float*)d_in[15];

  float* out_f       = (float*)d_out;                      // [4096,4096] fp32
  float* new_state_f = out_f + (size_t)BENT * MDIM;        // [4096,512]  fp32

  char* ws = (char*)d_ws;
  auto alloc = [&](size_t elems, size_t esz) {
    char* p = ws;
    ws += (elems * esz + 255) & ~(size_t)255;
    return p;
  };
  bf16_t* WinT   = (bf16_t*)alloc((size_t)HIN * MDIM, 2);      // [512,4096]
  bf16_t* WencT  = (bf16_t*)alloc((size_t)HENC * HSTATE, 2);   // [256,512]
  bf16_t* WcoreT = (bf16_t*)alloc((size_t)HCORE * 2*HENC, 2);  // [512,512]
  bf16_t* WctxT  = (bf16_t*)alloc((size_t)HCTX * HCORE, 2);    // [256,512]
  bf16_t* WrecT  = (bf16_t*)alloc((size_t)HSTATE * 1024, 2);   // [512,1024]
  bf16_t* WoutT  = (bf16_t*)alloc((size_t)MDIM * HSTATE, 2);   // [4096,512]
  bf16_t* state1 = (bf16_t*)alloc((size_t)BENT * HENC, 2);     // [4096,256]
  bf16_t* total  = (bf16_t*)alloc((size_t)BENT * 1024, 2);     // [4096,1024]
  bf16_t* ns_b   = (bf16_t*)alloc((size_t)BENT * HSTATE, 2);   // [4096,512]
  bf16_t* core_in  = (bf16_t*)alloc((size_t)NPAIR * 2*HENC, 2);// [28672,512]
  bf16_t* core_out = (bf16_t*)alloc((size_t)NPAIR * HCORE, 2); // [28672,512]
  bf16_t* context  = (bf16_t*)alloc((size_t)NPAIR * HCTX, 2);  // [28672,256]
  float*  att      = (float*)alloc((size_t)NPAIR, 4);          // [28672]

  dim3 tb(32, 8);
  // weight transposes+convert [K,N] fp32 -> [N,K] bf16
  transpose_k<<<dim3(HIN/32,   MDIM/32),   tb, 0, stream>>>(W_in,   WinT,   MDIM,   HIN);
  transpose_k<<<dim3(HENC/32,  HSTATE/32), tb, 0, stream>>>(W_enc,  WencT,  HSTATE, HENC);
  transpose_k<<<dim3(HCORE/32, (2*HENC)/32), tb, 0, stream>>>(W_core, WcoreT, 2*HENC, HCORE);
  transpose_k<<<dim3(HCTX/32,  HCORE/32),  tb, 0, stream>>>(W_ctx,  WctxT,  HCORE,  HCTX);
  transpose_k<<<dim3(HSTATE/32, 1024/32),  tb, 0, stream>>>(W_rec,  WrecT,  1024,   HSTATE);
  transpose_k<<<dim3(MDIM/32,  HSTATE/32), tb, 0, stream>>>(W_out,  WoutT,  HSTATE, MDIM);

  // x = elu(inputs @ W_in + b_in) -> total[:, 512:1024]   (A fp32, cvt in staging)
  gemm_bt<1, 1, float><<<dim3(HIN/64, BENT/64), 256, 0, stream>>>(
      inputs, WinT, b_in, total + 512, nullptr, BENT, HIN, MDIM, 1024, 0);
  // state1 = relu(state @ W_enc + b_enc)                  (A fp32)
  gemm_bt<2, 1, float><<<dim3(HENC/64, BENT/64), 256, 0, stream>>>(
      state, WencT, b_enc, state1, nullptr, BENT, HENC, HSTATE, HENC, 0);
  // core_in gather
  gather_k<<<NPAIR, 64, 0, stream>>>(state1, core_in);
  // core_out = relu(core_in @ W_core + b_core)
  gemm_bt<2, 1, bf16_t><<<dim3(HCORE/64, NPAIR/64), 256, 0, stream>>>(
      core_in, WcoreT, b_core, core_out, nullptr, NPAIR, HCORE, 2*HENC, HCORE, 0);
  // context = relu(core_out @ W_ctx + b_ctx)
  gemm_bt<2, 1, bf16_t><<<dim3(HCTX/64, NPAIR/64), 256, 0, stream>>>(
      core_out, WctxT, b_ctx, context, nullptr, NPAIR, HCTX, HCORE, HCTX, 0);
  // attention = sigmoid(core_out @ W_att + b_att)
  att_k<<<NPAIR/4, 256, 0, stream>>>(core_out, W_att, b_att, att);
  // effect sum + concat into total[:, 0:512]
  effect_k<<<BENT, 256, 0, stream>>>(att, context, state1, total);
  // new_state = sigmoid(total @ W_rec + b_rec): bf16 copy (ws) + fp32 (d_out)
  gemm_bt<3, 3, bf16_t><<<dim3(HSTATE/64, BENT/64), 256, 0, stream>>>(
      total, WrecT, b_rec, ns_b, new_state_f, BENT, HSTATE, 1024, HSTATE, HSTATE);
  // out = sigmoid(new_state @ W_out + b_out): fp32 only
  gemm_bt<3, 2, bf16_t><<<dim3(MDIM/64, BENT/64), 256, 0, stream>>>(
      ns_b, WoutT, b_out, nullptr, out_f, BENT, MDIM, HSTATE, MDIM, MDIM);
}